// Round 2
// baseline (456.818 us; speedup 1.0000x reference)
//
#include <hip/hip_runtime.h>
#include <stdint.h>
#include <math.h>

// MASK_SCHEME selects the JAX threefry bit-stream layout:
//   0 = partitionable counter-mode, 32-bit out = LOW word          (WRONG — R0 result)
//   1 = partitionable counter-mode, 32-bit out = y0 ^ y1  (JAX >= 0.4.30 default)
//   2 = original (pre-partitionable) split-halves scheme  (fallback if R1 fails)
#ifndef MASK_SCHEME
#define MASK_SCHEME 1
#endif

constexpr int Bn = 4, Hn = 16, Sn = 1024, Dn = 64;
constexpr int TQ = 64, TK = 64, NT = 256;
constexpr int LST = 68;  // padded LDS row stride (floats)

__device__ __forceinline__ void tf_round(uint32_t& x0, uint32_t& x1, const int r) {
  x0 += x1;
  x1 = (x1 << r) | (x1 >> (32 - r));  // v_alignbit_b32
  x1 ^= x0;
}

// threefry2x32 with key (0, 42) == jax.random.key(42)
__device__ __forceinline__ void threefry2x32_k042(uint32_t x0, uint32_t x1,
                                                  uint32_t& o0, uint32_t& o1) {
  const uint32_t k0 = 0u, k1v = 42u;
  const uint32_t k2v = k0 ^ k1v ^ 0x1BD11BDAu;
  x0 += k0; x1 += k1v;
  tf_round(x0, x1, 13); tf_round(x0, x1, 15); tf_round(x0, x1, 26); tf_round(x0, x1, 6);
  x0 += k1v; x1 += k2v + 1u;
  tf_round(x0, x1, 17); tf_round(x0, x1, 29); tf_round(x0, x1, 16); tf_round(x0, x1, 24);
  x0 += k2v; x1 += k0 + 2u;
  tf_round(x0, x1, 13); tf_round(x0, x1, 15); tf_round(x0, x1, 26); tf_round(x0, x1, 6);
  x0 += k0; x1 += k1v + 3u;
  tf_round(x0, x1, 17); tf_round(x0, x1, 29); tf_round(x0, x1, 16); tf_round(x0, x1, 24);
  x0 += k1v; x1 += k2v + 4u;
  tf_round(x0, x1, 13); tf_round(x0, x1, 15); tf_round(x0, x1, 26); tf_round(x0, x1, 6);
  x0 += k2v; x1 += k0 + 5u;
  o0 = x0; o1 = x1;
}

// jax.random.uniform f32 from 32 bits, then keep = u < 0.9f (p = 1-0.1, f32)
__device__ __forceinline__ int keep_from_bits(uint32_t bits) {
  float u = __uint_as_float((bits >> 9) | 0x3f800000u) - 1.0f;
  return u < 0.9f;
}

// single-element fallback (used only when ws is too small for the bitmask)
__device__ __forceinline__ int keep_bit(uint32_t j) {
#if MASK_SCHEME == 2
  const uint32_t half = (uint32_t)Bn * Hn * Sn * Sn / 2u;
  uint32_t y0, y1;
  if (j < half) { threefry2x32_k042(j, j + half, y0, y1); return keep_from_bits(y0); }
  threefry2x32_k042(j - half, j, y0, y1); return keep_from_bits(y1);
#else
  uint32_t y0, y1;
  threefry2x32_k042(0u, j, y0, y1);  // count_hi = 0 (j < 2^32), count_lo = j
#if MASK_SCHEME == 0
  return keep_from_bits(y1);
#else
  return keep_from_bits(y0 ^ y1);
#endif
#endif
}

// Pass 1: build packed dropout bitmask in workspace (bit j of mask == keep).
// Each block covers 1024 consecutive elements; wave-contiguous lanes -> __ballot pack.
__global__ __launch_bounds__(NT) void mask_kernel(uint64_t* __restrict__ mask) {
  const uint32_t t = threadIdx.x;
#if MASK_SCHEME == 2
  // thread handles counter i; produces bits for j=i (y0) and j=i+half (y1)
#pragma unroll
  for (int it = 0; it < 4; ++it) {
    const uint32_t half = (uint32_t)Bn * Hn * Sn * Sn / 2u;
    uint32_t i = blockIdx.x * (NT * 4) + (uint32_t)it * NT + t;
    uint32_t y0, y1;
    threefry2x32_k042(i, i + half, y0, y1);
    uint64_t b0 = __ballot(keep_from_bits(y0));
    uint64_t b1 = __ballot(keep_from_bits(y1));
    if ((t & 63u) == 0u) {
      mask[i >> 6] = b0;
      mask[(i + half) >> 6] = b1;
    }
  }
#else
#pragma unroll
  for (int it = 0; it < 4; ++it) {
    uint32_t j = blockIdx.x * (NT * 4) + (uint32_t)it * NT + t;
    uint32_t y0, y1;
    threefry2x32_k042(0u, j, y0, y1);
#if MASK_SCHEME == 0
    uint32_t bits = y1;
#else
    uint32_t bits = y0 ^ y1;
#endif
    uint64_t b = __ballot(keep_from_bits(bits));
    if ((t & 63u) == 0u) mask[j >> 6] = b;
  }
#endif
}

// Pass 2: flash attention, fp32. One block per (b,h, 64-query tile).
// Online softmax with UNMASKED running (m,l); dropout mask applied only to the
// P fed into the PV accumulation; final scale 1/(l*0.9).
template <bool USEWS>
__global__ __launch_bounds__(NT) void attn_kernel(
    const float* __restrict__ Q, const float* __restrict__ K,
    const float* __restrict__ V, const int* __restrict__ scale_ptr,
    const uint64_t* __restrict__ mask, float* __restrict__ out) {
  __shared__ float Qt[Dn][LST];       // Qt[d][qi]
  __shared__ float KP[TK][LST];       // phase A: Kt[d][kj]; phase B: Pt[kj][qi]
  __shared__ float Vs[TK][LST];       // Vs[kj][dj]
  __shared__ float red[TQ][17];       // +1 pad: column reads would be 32-way else
  __shared__ float mrow[TQ], lrow[TQ], arow[TQ];

  const int t = threadIdx.x;
  const int b = blockIdx.z, h = blockIdx.y;
  const int qbase = blockIdx.x * TQ;
  const int qi0 = 4 * (t >> 4);       // 4 query rows per thread
  const int c0  = 4 * (t & 15);       // 4 key cols (S gemm) / 4 dims (PV gemm)

  const float scale = (float)(*scale_ptr);

  const size_t bh = (size_t)b * Hn + h;
  const float* Qp = Q + (bh * Sn + (size_t)qbase) * Dn;
  const float* Kp = K + bh * Sn * Dn;
  const float* Vp = V + bh * Sn * Dn;
  const uint32_t rowlin0 = (uint32_t)(b * Hn + h) * (uint32_t)Sn + (uint32_t)(qbase + qi0);

  // stage Q transposed (coalesced global float4, scattered b32 LDS writes)
  {
    const int r = t >> 2, quar = t & 3;
    const float* src = Qp + r * Dn + quar * 16;
#pragma unroll
    for (int i = 0; i < 4; ++i) {
      float4 v = *(const float4*)(src + 4 * i);
      int d = quar * 16 + 4 * i;
      Qt[d + 0][r] = v.x; Qt[d + 1][r] = v.y; Qt[d + 2][r] = v.z; Qt[d + 3][r] = v.w;
    }
  }
  if (t < TQ) { mrow[t] = -INFINITY; lrow[t] = 0.0f; }

  float o[4][4] = {};

  for (int kt = 0; kt < Sn / TK; ++kt) {
    const int kbase = kt * TK;
    __syncthreads();  // prev tile's PV reads of KP/Vs done; Qt visible on kt==0
    {
      const int r = t >> 2, quar = t & 3;
      const float* ks = Kp + (size_t)(kbase + r) * Dn + quar * 16;
      const float* vs = Vp + (size_t)(kbase + r) * Dn + quar * 16;
#pragma unroll
      for (int i = 0; i < 4; ++i) {
        const int d = quar * 16 + 4 * i;
        float4 kv = *(const float4*)(ks + 4 * i);
        KP[d + 0][r] = kv.x; KP[d + 1][r] = kv.y; KP[d + 2][r] = kv.z; KP[d + 3][r] = kv.w;
        *(float4*)&Vs[r][d] = *(const float4*)(vs + 4 * i);
      }
    }
    __syncthreads();

    // S gemm: s[r][c] = scale * sum_d Qt[d][qi0+r] * Kt[d][c0+c]
    float s[4][4];
#pragma unroll
    for (int r = 0; r < 4; ++r)
#pragma unroll
      for (int c = 0; c < 4; ++c) s[r][c] = 0.0f;
#pragma unroll 4
    for (int d = 0; d < Dn; ++d) {
      const float4 qv = *(const float4*)&Qt[d][qi0];
      const float4 kv = *(const float4*)&KP[d][c0];
      const float qa[4] = {qv.x, qv.y, qv.z, qv.w};
      const float ka[4] = {kv.x, kv.y, kv.z, kv.w};
#pragma unroll
      for (int r = 0; r < 4; ++r)
#pragma unroll
        for (int c = 0; c < 4; ++c) s[r][c] = fmaf(qa[r], ka[c], s[r][c]);
    }
#pragma unroll
    for (int r = 0; r < 4; ++r)
#pragma unroll
      for (int c = 0; c < 4; ++c) s[r][c] *= scale;

    // row-max partials -> reduce -> m_new, alpha
#pragma unroll
    for (int r = 0; r < 4; ++r)
      red[qi0 + r][t & 15] = fmaxf(fmaxf(s[r][0], s[r][1]), fmaxf(s[r][2], s[r][3]));
    __syncthreads();
    if (t < TQ) {
      float mx = red[t][0];
#pragma unroll
      for (int i = 1; i < 16; ++i) mx = fmaxf(mx, red[t][i]);
      const float mo = mrow[t];
      const float mn = fmaxf(mo, mx);
      mrow[t] = mn;
      arow[t] = __expf(mo - mn);  // exp(-inf)=0 on first tile
    }
    __syncthreads();

    // p = exp(s-m); UNMASKED row-sum partials; masked transpose-write Pt (=KP)
    float p[4][4];
    uint32_t nib[4];
#pragma unroll
    for (int r = 0; r < 4; ++r) {
      const float mn = mrow[qi0 + r];
      if constexpr (USEWS) {
        const uint64_t w = mask[(size_t)(rowlin0 + (uint32_t)r) * (Sn / 64) + (kbase >> 6)];
        nib[r] = (uint32_t)(w >> c0) & 0xFu;
      } else {
        const uint32_t jb = (rowlin0 + (uint32_t)r) * (uint32_t)Sn + (uint32_t)(kbase + c0);
        nib[r] = (uint32_t)keep_bit(jb) | ((uint32_t)keep_bit(jb + 1) << 1) |
                 ((uint32_t)keep_bit(jb + 2) << 2) | ((uint32_t)keep_bit(jb + 3) << 3);
      }
      float ls = 0.0f;
#pragma unroll
      for (int c = 0; c < 4; ++c) { p[r][c] = __expf(s[r][c] - mn); ls += p[r][c]; }
      red[qi0 + r][t & 15] = ls;
    }
#pragma unroll
    for (int r = 0; r < 4; ++r) {  // rescale accumulator by alpha
      const float a = arow[qi0 + r];
#pragma unroll
      for (int c = 0; c < 4; ++c) o[r][c] *= a;
    }
#pragma unroll
    for (int c = 0; c < 4; ++c) {  // Pt[kj][qi0..qi0+3] as one float4
      float4 pm;
      pm.x = ((nib[0] >> c) & 1u) ? p[0][c] : 0.0f;
      pm.y = ((nib[1] >> c) & 1u) ? p[1][c] : 0.0f;
      pm.z = ((nib[2] >> c) & 1u) ? p[2][c] : 0.0f;
      pm.w = ((nib[3] >> c) & 1u) ? p[3][c] : 0.0f;
      *(float4*)&KP[c0 + c][qi0] = pm;
    }
    __syncthreads();
    if (t < TQ) {
      float ls = 0.0f;
#pragma unroll
      for (int i = 0; i < 16; ++i) ls += red[t][i];
      lrow[t] = lrow[t] * arow[t] + ls;
    }
    // PV gemm: o[qi][dj] += sum_kj Pt[kj][qi] * Vs[kj][dj]
#pragma unroll 4
    for (int kk = 0; kk < TK; ++kk) {
      const float4 pv = *(const float4*)&KP[kk][qi0];
      const float4 vv = *(const float4*)&Vs[kk][c0];
      const float pa[4] = {pv.x, pv.y, pv.z, pv.w};
      const float va[4] = {vv.x, vv.y, vv.z, vv.w};
#pragma unroll
      for (int r = 0; r < 4; ++r)
#pragma unroll
        for (int c = 0; c < 4; ++c) o[r][c] = fmaf(pa[r], va[c], o[r][c]);
    }
  }

  __syncthreads();  // lrow final
#pragma unroll
  for (int r = 0; r < 4; ++r) {
    const float invl = 1.0f / (lrow[qi0 + r] * 0.9f);  // softmax denom * (1-p)
    float4 ov;
    ov.x = o[r][0] * invl; ov.y = o[r][1] * invl;
    ov.z = o[r][2] * invl; ov.w = o[r][3] * invl;
    *(float4*)(out + (bh * Sn + (size_t)(qbase + qi0 + r)) * Dn + c0) = ov;
  }
}

extern "C" void kernel_launch(void* const* d_in, const int* in_sizes, int n_in,
                              void* d_out, int out_size, void* d_ws, size_t ws_size,
                              hipStream_t stream) {
  const float* Q = (const float*)d_in[0];
  const float* K = (const float*)d_in[1];
  const float* V = (const float*)d_in[2];
  const int* sf  = (const int*)d_in[3];
  float* out = (float*)d_out;

  const uint32_t NTOT = (uint32_t)Bn * Hn * Sn * Sn;  // 67108864 mask bits
  const size_t mask_bytes = (size_t)NTOT / 8;         // 8 MiB

  dim3 grid(Sn / TQ, Hn, Bn);

  if (ws_size >= mask_bytes) {
    uint64_t* mask = (uint64_t*)d_ws;
#if MASK_SCHEME == 2
    mask_kernel<<<NTOT / 2 / (NT * 4), NT, 0, stream>>>(mask);
#else
    mask_kernel<<<NTOT / (NT * 4), NT, 0, stream>>>(mask);
#endif
    attn_kernel<true><<<grid, NT, 0, stream>>>(Q, K, V, sf, mask, out);
  } else {
    attn_kernel<false><<<grid, NT, 0, stream>>>(Q, K, V, sf, nullptr, out);
  }
}

// Round 3
// 213.929 us; speedup vs baseline: 2.1354x; 2.1354x over previous
//
#include <hip/hip_runtime.h>
#include <stdint.h>
#include <math.h>

// Attention: out = dropout(softmax(8 * Q K^T)) V, B=4 H=16 S=1024 D=64 fp32.
// Single fused kernel:
//  - QK^T via bf16 MFMA with 2-term split (QhKh + QlKh + QhKl): ~1e-3 logit err
//  - online softmax in MFMA C-layout (m89: col=lane&15, row=quad*4+reg)
//  - JAX threefry dropout (scheme: counter-mode, bits = y0^y1 — VERIFIED R2)
//    evaluated LAZILY: only where s - m > -25 (p > 1.4e-11); skipped bits
//    contribute <= 1e-10 masked or not.
//  - P -> LDS (bf16) -> A-layout reads (m120 pattern) -> PV via bf16 MFMA.

constexpr int Bn = 4, Hn = 16, Sn = 1024, Dn = 64;
constexpr int TQ = 64, TK = 64, NT = 256;
constexpr int KST = 72;  // LDS row stride in bf16 elems (64 + 8 pad, keeps 16B align)

typedef short s16x8 __attribute__((ext_vector_type(8)));
typedef float f32x4 __attribute__((ext_vector_type(4)));

__device__ __forceinline__ uint16_t f2bf(float x) {  // RNE float->bf16
  uint32_t u = __float_as_uint(x);
  return (uint16_t)((u + 0x7fffu + ((u >> 16) & 1u)) >> 16);
}
__device__ __forceinline__ float bf2f(uint16_t h) {
  return __uint_as_float(((uint32_t)h) << 16);
}

__device__ __forceinline__ void tf_round(uint32_t& x0, uint32_t& x1, const int r) {
  x0 += x1;
  x1 = (x1 << r) | (x1 >> (32 - r));
  x1 ^= x0;
}

// threefry2x32, key(42)=(0,42), counter (0, j), bits = y0^y1  [VERIFIED R2]
__device__ __noinline__ int keep_bit(uint32_t j) {
  uint32_t x0 = 0u, x1 = j;
  const uint32_t k0 = 0u, k1v = 42u;
  const uint32_t k2v = k0 ^ k1v ^ 0x1BD11BDAu;
  x0 += k0; x1 += k1v;
  tf_round(x0, x1, 13); tf_round(x0, x1, 15); tf_round(x0, x1, 26); tf_round(x0, x1, 6);
  x0 += k1v; x1 += k2v + 1u;
  tf_round(x0, x1, 17); tf_round(x0, x1, 29); tf_round(x0, x1, 16); tf_round(x0, x1, 24);
  x0 += k2v; x1 += k0 + 2u;
  tf_round(x0, x1, 13); tf_round(x0, x1, 15); tf_round(x0, x1, 26); tf_round(x0, x1, 6);
  x0 += k0; x1 += k1v + 3u;
  tf_round(x0, x1, 17); tf_round(x0, x1, 29); tf_round(x0, x1, 16); tf_round(x0, x1, 24);
  x0 += k1v; x1 += k2v + 4u;
  tf_round(x0, x1, 13); tf_round(x0, x1, 15); tf_round(x0, x1, 26); tf_round(x0, x1, 6);
  x0 += k2v; x1 += k0 + 5u;
  uint32_t bits = x0 ^ x1;
  float u = __uint_as_float((bits >> 9) | 0x3f800000u) - 1.0f;
  return u < 0.9f;
}

__global__ __launch_bounds__(NT) void attn_mfma(
    const float* __restrict__ Q, const float* __restrict__ K,
    const float* __restrict__ V, const int* __restrict__ scale_ptr,
    float* __restrict__ out) {
  __shared__ uint16_t KhS[TK * KST];      // K tile, bf16 high   [key][d]
  __shared__ uint16_t KlS[TK * KST];      // K tile, bf16 resid  [key][d]
  __shared__ uint16_t VtS[Dn * KST];      // V tile, transposed  [dv][key]
  __shared__ uint16_t PS[4 * 16 * KST];   // per-wave P          [q(16)][key(64)]

  const int t = threadIdx.x;
  const int w = t >> 6;        // wave 0..3 -> q rows w*16..w*16+15
  const int lane = t & 63;
  const int l16 = lane & 15;
  const int quad = lane >> 4;

  const int b = blockIdx.z, h = blockIdx.y;
  const int qbase = blockIdx.x * TQ;
  const size_t bh = (size_t)b * Hn + h;
  const float scale = (float)(*scale_ptr);

  const float* Kp = K + bh * Sn * Dn;
  const float* Vp = V + bh * Sn * Dn;

  // ---- Q fragments (held in registers for the whole K sweep) ----
  // A-frag layout (m120): lane holds A[m=lane&15][k=quad*8+j], j=0..7.
  const int qrow = qbase + w * 16 + l16;
  const float* Qp = Q + (bh * Sn + (size_t)qrow) * Dn;
  s16x8 qh[2], ql[2];
#pragma unroll
  for (int ks = 0; ks < 2; ++ks) {
    const float* src = Qp + ks * 32 + quad * 8;
    float4 x0 = *(const float4*)(src);
    float4 x1 = *(const float4*)(src + 4);
    float xv[8] = {x0.x, x0.y, x0.z, x0.w, x1.x, x1.y, x1.z, x1.w};
#pragma unroll
    for (int j = 0; j < 8; ++j) {
      uint16_t hb = f2bf(xv[j]);
      qh[ks][j] = (short)hb;
      ql[ks][j] = (short)f2bf(xv[j] - bf2f(hb));
    }
  }

  const int kr = t >> 2;  // staging: key row 0..63
  const int qd = t & 3;   // staging: 16-float column quarter

  float m_r[4], l_r[4];
#pragma unroll
  for (int r = 0; r < 4; ++r) { m_r[r] = -INFINITY; l_r[r] = 0.0f; }
  f32x4 o_acc[4];
#pragma unroll
  for (int c = 0; c < 4; ++c) o_acc[c] = (f32x4){0.f, 0.f, 0.f, 0.f};

  // dropout bit index base: row_lin = (b*H+h)*S + q ; j = row_lin*S + col
  const uint32_t rowlin = ((uint32_t)(b * Hn + h)) * (uint32_t)Sn +
                          (uint32_t)(qbase + w * 16 + quad * 4);

  for (int kt = 0; kt < Sn / TK; ++kt) {
    const int kbase = kt * TK;
    __syncthreads();  // previous tile's LDS reads complete

    // ---- stage K (split bf16) and V (transposed bf16) ----
    {
      const float* ksrc = Kp + (size_t)(kbase + kr) * Dn + qd * 16;
#pragma unroll
      for (int half = 0; half < 2; ++half) {
        float4 a = *(const float4*)(ksrc + half * 8);
        float4 b2 = *(const float4*)(ksrc + half * 8 + 4);
        float xs[8] = {a.x, a.y, a.z, a.w, b2.x, b2.y, b2.z, b2.w};
        s16x8 hv, lv;
#pragma unroll
        for (int j = 0; j < 8; ++j) {
          uint16_t hb = f2bf(xs[j]);
          hv[j] = (short)hb;
          lv[j] = (short)f2bf(xs[j] - bf2f(hb));
        }
        *(s16x8*)&KhS[kr * KST + qd * 16 + half * 8] = hv;
        *(s16x8*)&KlS[kr * KST + qd * 16 + half * 8] = lv;
      }
      const float* vsrc = Vp + (size_t)(kbase + kr) * Dn + qd * 16;
#pragma unroll
      for (int half = 0; half < 2; ++half) {
        float4 a = *(const float4*)(vsrc + half * 8);
        float4 b2 = *(const float4*)(vsrc + half * 8 + 4);
        float xs[8] = {a.x, a.y, a.z, a.w, b2.x, b2.y, b2.z, b2.w};
#pragma unroll
        for (int j = 0; j < 8; ++j)
          VtS[(qd * 16 + half * 8 + j) * KST + kr] = f2bf(xs[j]);
      }
    }
    __syncthreads();

    // ---- QK^T: S[q][key], split-bf16 3-MFMA ----
    f32x4 sacc[4];
#pragma unroll
    for (int c = 0; c < 4; ++c) sacc[c] = (f32x4){0.f, 0.f, 0.f, 0.f};
#pragma unroll
    for (int ks = 0; ks < 2; ++ks) {
#pragma unroll
      for (int c = 0; c < 4; ++c) {
        const s16x8 bh_ = *(const s16x8*)&KhS[(c * 16 + l16) * KST + ks * 32 + quad * 8];
        const s16x8 bl_ = *(const s16x8*)&KlS[(c * 16 + l16) * KST + ks * 32 + quad * 8];
        sacc[c] = __builtin_amdgcn_mfma_f32_16x16x32_bf16(qh[ks], bh_, sacc[c], 0, 0, 0);
        sacc[c] = __builtin_amdgcn_mfma_f32_16x16x32_bf16(ql[ks], bh_, sacc[c], 0, 0, 0);
        sacc[c] = __builtin_amdgcn_mfma_f32_16x16x32_bf16(qh[ks], bl_, sacc[c], 0, 0, 0);
      }
    }

    // ---- online softmax (C-layout: lane holds rows quad*4+r, col c*16+l16) ----
    float mx[4];
#pragma unroll
    for (int r = 0; r < 4; ++r) {
      mx[r] = sacc[0][r] * scale;
#pragma unroll
      for (int c = 1; c < 4; ++c) mx[r] = fmaxf(mx[r], sacc[c][r] * scale);
#pragma unroll
      for (int d = 1; d < 16; d <<= 1) mx[r] = fmaxf(mx[r], __shfl_xor(mx[r], d));
    }
    float al[4];
#pragma unroll
    for (int r = 0; r < 4; ++r) {
      const float mn = fmaxf(m_r[r], mx[r]);
      al[r] = __expf(m_r[r] - mn);  // 0 on first tile (exp(-inf))
      m_r[r] = mn;
    }
#pragma unroll
    for (int c = 0; c < 4; ++c)
#pragma unroll
      for (int r = 0; r < 4; ++r) o_acc[c][r] *= al[r];

    float rs[4] = {0.f, 0.f, 0.f, 0.f};
#pragma unroll
    for (int c = 0; c < 4; ++c) {
#pragma unroll
      for (int r = 0; r < 4; ++r) {
        const float d = sacc[c][r] * scale - m_r[r];
        float pv = __expf(d);
        rs[r] += pv;  // UNMASKED row sum (softmax normalizes before dropout)
        // lazy exact dropout: only entries that can matter
        if (d > -25.0f) {
          const uint32_t j = (rowlin + (uint32_t)r) * (uint32_t)Sn +
                             (uint32_t)(kbase + c * 16 + l16);
          if (!keep_bit(j)) pv = 0.0f;
        }
        PS[(w * 16 + quad * 4 + r) * KST + c * 16 + l16] = f2bf(pv);
      }
    }
#pragma unroll
    for (int r = 0; r < 4; ++r) {
#pragma unroll
      for (int d = 1; d < 16; d <<= 1) rs[r] += __shfl_xor(rs[r], d);
      l_r[r] = l_r[r] * al[r] + rs[r];
    }

    // ---- PV: O += P V  (same-wave LDS RAW; DS pipe is in-order per wave) ----
#pragma unroll
    for (int ks2 = 0; ks2 < 2; ++ks2) {
      const s16x8 pa = *(const s16x8*)&PS[(w * 16 + l16) * KST + ks2 * 32 + quad * 8];
#pragma unroll
      for (int c = 0; c < 4; ++c) {
        const s16x8 vb = *(const s16x8*)&VtS[(c * 16 + l16) * KST + ks2 * 32 + quad * 8];
        o_acc[c] = __builtin_amdgcn_mfma_f32_16x16x32_bf16(pa, vb, o_acc[c], 0, 0, 0);
      }
    }
  }

  // ---- epilogue: out = O / (l * 0.9) ----
  float inv[4];
#pragma unroll
  for (int r = 0; r < 4; ++r) inv[r] = 1.0f / (l_r[r] * 0.9f);
#pragma unroll
  for (int c = 0; c < 4; ++c)
#pragma unroll
    for (int r = 0; r < 4; ++r)
      out[(bh * Sn + (size_t)(qbase + w * 16 + quad * 4 + r)) * Dn + c * 16 + l16] =
          o_acc[c][r] * inv[r];
}

extern "C" void kernel_launch(void* const* d_in, const int* in_sizes, int n_in,
                              void* d_out, int out_size, void* d_ws, size_t ws_size,
                              hipStream_t stream) {
  const float* Q = (const float*)d_in[0];
  const float* K = (const float*)d_in[1];
  const float* V = (const float*)d_in[2];
  const int* sf = (const int*)d_in[3];
  float* out = (float*)d_out;

  dim3 grid(Sn / TQ, Hn, Bn);  // 16 x 16 x 4 = 1024 blocks
  attn_mfma<<<grid, NT, 0, stream>>>(Q, K, V, sf, out);
}

// Round 4
// 207.592 us; speedup vs baseline: 2.2006x; 1.0305x over previous
//
#include <hip/hip_runtime.h>
#include <stdint.h>
#include <math.h>

// Attention: out = dropout(softmax(8 * Q K^T)) V, B=4 H=16 S=1024 D=64 fp32.
// R4 structure:
//  - prep_kv: once-per-launch conversion of K -> (Kh,Kl) bf16 split and
//    V -> V^T, tiled per (head, ktile), bf16, with XOR chunk swizzle baked
//    into the global layout (chunk c of row r stored at c^(r&7)) so the main
//    kernel can DMA tiles via global_load_lds (lane-contiguous, unpadded LDS)
//    and still read MFMA B-fragments conflict-free (2-way max = free).
//  - attn_mfma2: TQ=128 flash kernel, bf16 MFMA 16x16x32.
//    QK^T split-bf16 3-MFMA (QhKh+QlKh+QhKl); Q pre-scaled by scale_factor.
//    Online softmax in C-layout (col=lane&15, row=quad*4+reg).
//    JAX threefry dropout (counter-mode, bits=y0^y1 — VERIFIED R2), lazy:
//    only where s-m > -11 (skipped entries contribute <= ~1e-4).
//    P -> per-wave LDS (padded stride 72) -> A-frags -> PV MFMA.

constexpr int Bn = 4, Hn = 16, Sn = 1024, Dn = 64;
constexpr int NT = 256;
constexpr int TQ = 128, TK = 64;
constexpr int PST = 72;  // PS row stride in bf16 (16B-aligned; A-frag reads 2-way only)

typedef short s16x8 __attribute__((ext_vector_type(8)));
typedef float f32x4 __attribute__((ext_vector_type(4)));

__device__ __forceinline__ uint16_t f2bf(float x) {  // RNE float->bf16
  uint32_t u = __float_as_uint(x);
  return (uint16_t)((u + 0x7fffu + ((u >> 16) & 1u)) >> 16);
}
__device__ __forceinline__ float bf2f(uint16_t h) {
  return __uint_as_float(((uint32_t)h) << 16);
}

__device__ __forceinline__ void tf_round(uint32_t& x0, uint32_t& x1, const int r) {
  x0 += x1;
  x1 = (x1 << r) | (x1 >> (32 - r));
  x1 ^= x0;
}

// threefry2x32, key(42)=(0,42), counter (0, j), bits = y0^y1  [VERIFIED R2]
__device__ __noinline__ int keep_bit(uint32_t j) {
  uint32_t x0 = 0u, x1 = j;
  const uint32_t k0 = 0u, k1v = 42u;
  const uint32_t k2v = k0 ^ k1v ^ 0x1BD11BDAu;
  x0 += k0; x1 += k1v;
  tf_round(x0, x1, 13); tf_round(x0, x1, 15); tf_round(x0, x1, 26); tf_round(x0, x1, 6);
  x0 += k1v; x1 += k2v + 1u;
  tf_round(x0, x1, 17); tf_round(x0, x1, 29); tf_round(x0, x1, 16); tf_round(x0, x1, 24);
  x0 += k2v; x1 += k0 + 2u;
  tf_round(x0, x1, 13); tf_round(x0, x1, 15); tf_round(x0, x1, 26); tf_round(x0, x1, 6);
  x0 += k0; x1 += k1v + 3u;
  tf_round(x0, x1, 17); tf_round(x0, x1, 29); tf_round(x0, x1, 16); tf_round(x0, x1, 24);
  x0 += k1v; x1 += k2v + 4u;
  tf_round(x0, x1, 13); tf_round(x0, x1, 15); tf_round(x0, x1, 26); tf_round(x0, x1, 6);
  x0 += k2v; x1 += k0 + 5u;
  uint32_t bits = x0 ^ x1;
  float u = __uint_as_float((bits >> 9) | 0x3f800000u) - 1.0f;
  return u < 0.9f;
}

// ---------------- pre-pass: K split + V transpose, swizzled bf16 tiles ----------------
// Khg/Klg/Vtg layout: [bh][kt] tiles of 64 rows x 64 cols bf16 (4096 elems, 8KB,
// contiguous). Within a row, 16B chunk c stored at position c ^ (row & 7).
__global__ __launch_bounds__(NT) void prep_kv(const float* __restrict__ K,
                                              const float* __restrict__ V,
                                              uint16_t* __restrict__ Khg,
                                              uint16_t* __restrict__ Klg,
                                              uint16_t* __restrict__ Vtg) {
  __shared__ float Vl[TK][Dn + 1];
  const int t = threadIdx.x;
  const int kt = blockIdx.x;   // 0..15
  const int bh = blockIdx.y;   // 0..63
  const int r = t >> 2, qd = t & 3;
  const size_t tile = ((size_t)bh * 16 + kt) * 4096;
  const float* ksrc = K + ((size_t)bh * Sn + (size_t)(kt * TK + r)) * Dn + qd * 16;
  const float* vsrc = V + ((size_t)bh * Sn + (size_t)(kt * TK + r)) * Dn + qd * 16;

#pragma unroll
  for (int half = 0; half < 2; ++half) {
    float4 a = *(const float4*)(ksrc + half * 8);
    float4 b = *(const float4*)(ksrc + half * 8 + 4);
    float xs[8] = {a.x, a.y, a.z, a.w, b.x, b.y, b.z, b.w};
    s16x8 hv, lv;
#pragma unroll
    for (int j = 0; j < 8; ++j) {
      uint16_t hb = f2bf(xs[j]);
      hv[j] = (short)hb;
      lv[j] = (short)f2bf(xs[j] - bf2f(hb));
    }
    const int sc = (qd * 2 + half) ^ (r & 7);
    *(s16x8*)&Khg[tile + (size_t)r * 64 + sc * 8] = hv;
    *(s16x8*)&Klg[tile + (size_t)r * 64 + sc * 8] = lv;
    // stage V tile rows into LDS (fp32)
    float4 va = *(const float4*)(vsrc + half * 8);
    float4 vb = *(const float4*)(vsrc + half * 8 + 4);
    *(float4*)&Vl[r][qd * 16 + half * 8] = va;
    *(float4*)&Vl[r][qd * 16 + half * 8 + 4] = vb;
  }
  __syncthreads();
  // transposed write: thread -> d-row r, key-quarter qd
#pragma unroll
  for (int half = 0; half < 2; ++half) {
    s16x8 ov;
#pragma unroll
    for (int j = 0; j < 8; ++j) ov[j] = (short)f2bf(Vl[qd * 16 + half * 8 + j][r]);
    const int sc = (qd * 2 + half) ^ (r & 7);
    *(s16x8*)&Vtg[tile + (size_t)r * 64 + sc * 8] = ov;
  }
}

// ---------------- main flash kernel, TQ=128 ----------------
__global__ __launch_bounds__(NT) void attn_mfma2(
    const float* __restrict__ Q, const uint16_t* __restrict__ Khg,
    const uint16_t* __restrict__ Klg, const uint16_t* __restrict__ Vtg,
    const int* __restrict__ scale_ptr, float* __restrict__ out) {
  __shared__ uint16_t KhS[TK * Dn];      // 8 KB, unpadded (DMA dest), swizzled rows
  __shared__ uint16_t KlS[TK * Dn];
  __shared__ uint16_t VtS[Dn * TK];
  __shared__ uint16_t PS[4 * 32 * PST];  // per-wave P, padded stride

  const int t = threadIdx.x;
  const int w = t >> 6;
  const int lane = t & 63;
  const int l16 = lane & 15;
  const int quad = lane >> 4;

  const int b = blockIdx.z, h = blockIdx.y;
  const int qbase = blockIdx.x * TQ;
  const int bh = b * Hn + h;
  const float qscale = (float)(*scale_ptr);

  // ---- Q A-frags (pre-scaled by scale_factor), 2 row-sets of 16 per wave ----
  s16x8 qh[2][2], ql[2][2];
#pragma unroll
  for (int u = 0; u < 2; ++u) {
    const int qrow = qbase + u * 64 + w * 16 + l16;
    const float* src = Q + ((size_t)bh * Sn + (size_t)qrow) * Dn;
#pragma unroll
    for (int ks = 0; ks < 2; ++ks) {
      float4 x0 = *(const float4*)(src + ks * 32 + quad * 8);
      float4 x1 = *(const float4*)(src + ks * 32 + quad * 8 + 4);
      float xv[8] = {x0.x, x0.y, x0.z, x0.w, x1.x, x1.y, x1.z, x1.w};
#pragma unroll
      for (int j = 0; j < 8; ++j) {
        const float xs = xv[j] * qscale;
        uint16_t hb = f2bf(xs);
        qh[u][ks][j] = (short)hb;
        ql[u][ks][j] = (short)f2bf(xs - bf2f(hb));
      }
    }
  }

  float m_r[2][4], l_r[2][4];
#pragma unroll
  for (int u = 0; u < 2; ++u)
#pragma unroll
    for (int r = 0; r < 4; ++r) { m_r[u][r] = -INFINITY; l_r[u][r] = 0.0f; }
  f32x4 o_acc[2][4];
#pragma unroll
  for (int u = 0; u < 2; ++u)
#pragma unroll
    for (int c = 0; c < 4; ++c) o_acc[u][c] = (f32x4){0.f, 0.f, 0.f, 0.f};

  const uint32_t hbase = (uint32_t)bh * (uint32_t)Sn;

  for (int kt = 0; kt < Sn / TK; ++kt) {
    const int kbase = kt * TK;
    __syncthreads();  // all waves done reading prev tile's LDS

    // ---- DMA staging: 24 x 1KB wave-segments; wave w -> segs {2w,2w+1} per array ----
    {
      const size_t tile = ((size_t)bh * 16 + kt) * 4096;
#pragma unroll
      for (int s = 0; s < 2; ++s) {
        const int eoff = (w * 2 + s) * 512 + lane * 8;  // elements
        __builtin_amdgcn_global_load_lds(
            (const __attribute__((address_space(1))) uint32_t*)(Khg + tile + eoff),
            (__attribute__((address_space(3))) uint32_t*)(KhS + eoff), 16, 0, 0);
        __builtin_amdgcn_global_load_lds(
            (const __attribute__((address_space(1))) uint32_t*)(Klg + tile + eoff),
            (__attribute__((address_space(3))) uint32_t*)(KlS + eoff), 16, 0, 0);
        __builtin_amdgcn_global_load_lds(
            (const __attribute__((address_space(1))) uint32_t*)(Vtg + tile + eoff),
            (__attribute__((address_space(3))) uint32_t*)(VtS + eoff), 16, 0, 0);
      }
    }
    __syncthreads();  // barrier drains vmcnt -> deposits visible

    // ---- QK^T: split-bf16 3-MFMA; B-frags shared across both row-sets ----
    f32x4 sacc[2][4];
#pragma unroll
    for (int u = 0; u < 2; ++u)
#pragma unroll
      for (int c = 0; c < 4; ++c) sacc[u][c] = (f32x4){0.f, 0.f, 0.f, 0.f};
#pragma unroll
    for (int ks = 0; ks < 2; ++ks) {
#pragma unroll
      for (int c = 0; c < 4; ++c) {
        const int boff = (c * 16 + l16) * 64 + (((ks * 4 + quad) ^ (l16 & 7)) * 8);
        const s16x8 bhv = *(const s16x8*)&KhS[boff];
        const s16x8 blv = *(const s16x8*)&KlS[boff];
#pragma unroll
        for (int u = 0; u < 2; ++u) {
          sacc[u][c] = __builtin_amdgcn_mfma_f32_16x16x32_bf16(qh[u][ks], bhv, sacc[u][c], 0, 0, 0);
          sacc[u][c] = __builtin_amdgcn_mfma_f32_16x16x32_bf16(ql[u][ks], bhv, sacc[u][c], 0, 0, 0);
          sacc[u][c] = __builtin_amdgcn_mfma_f32_16x16x32_bf16(qh[u][ks], blv, sacc[u][c], 0, 0, 0);
        }
      }
    }

    // ---- online softmax + lazy dropout + P store ----
#pragma unroll
    for (int u = 0; u < 2; ++u) {
      float mx[4], al[4];
#pragma unroll
      for (int r = 0; r < 4; ++r) {
        mx[r] = fmaxf(fmaxf(sacc[u][0][r], sacc[u][1][r]),
                      fmaxf(sacc[u][2][r], sacc[u][3][r]));
#pragma unroll
        for (int d = 1; d < 16; d <<= 1) mx[r] = fmaxf(mx[r], __shfl_xor(mx[r], d));
        const float mn = fmaxf(m_r[u][r], mx[r]);
        al[r] = __expf(m_r[u][r] - mn);  // 0 on first tile
        m_r[u][r] = mn;
      }
#pragma unroll
      for (int c = 0; c < 4; ++c)
#pragma unroll
        for (int r = 0; r < 4; ++r) o_acc[u][c][r] *= al[r];

      float rs[4] = {0.f, 0.f, 0.f, 0.f};
#pragma unroll
      for (int r = 0; r < 4; ++r) {
        float dv[4], pv[4];
#pragma unroll
        for (int c = 0; c < 4; ++c) {
          dv[c] = sacc[u][c][r] - m_r[u][r];
          pv[c] = __expf(dv[c]);
          rs[r] += pv[c];  // UNMASKED row sum (softmax normalizes before dropout)
        }
        const float dmx = fmaxf(fmaxf(dv[0], dv[1]), fmaxf(dv[2], dv[3]));
        if (dmx > -11.0f) {  // lazy dropout: only entries with p_rel > ~1.7e-5
          const uint32_t rq = hbase + (uint32_t)(qbase + u * 64 + w * 16 + quad * 4 + r);
#pragma unroll
          for (int c = 0; c < 4; ++c) {
            if (dv[c] > -11.0f) {
              const uint32_t j = rq * (uint32_t)Sn + (uint32_t)(kbase + c * 16 + l16);
              if (!keep_bit(j)) pv[c] = 0.0f;
            }
          }
        }
        const int prow = (w * 32 + u * 16 + quad * 4 + r) * PST;
#pragma unroll
        for (int c = 0; c < 4; ++c) PS[prow + c * 16 + l16] = f2bf(pv[c]);
      }
#pragma unroll
      for (int r = 0; r < 4; ++r) {
#pragma unroll
        for (int d = 1; d < 16; d <<= 1) rs[r] += __shfl_xor(rs[r], d);
        l_r[u][r] = l_r[u][r] * al[r] + rs[r];
      }
    }

    // ---- PV: O += P V  (same-wave LDS RAW; DS pipe in-order per wave) ----
#pragma unroll
    for (int ks2 = 0; ks2 < 2; ++ks2) {
      s16x8 pa[2];
#pragma unroll
      for (int u = 0; u < 2; ++u)
        pa[u] = *(const s16x8*)&PS[(w * 32 + u * 16 + l16) * PST + ks2 * 32 + quad * 8];
#pragma unroll
      for (int c = 0; c < 4; ++c) {
        const int voff = (c * 16 + l16) * 64 + (((ks2 * 4 + quad) ^ (l16 & 7)) * 8);
        const s16x8 vb = *(const s16x8*)&VtS[voff];
#pragma unroll
        for (int u = 0; u < 2; ++u)
          o_acc[u][c] = __builtin_amdgcn_mfma_f32_16x16x32_bf16(pa[u], vb, o_acc[u][c], 0, 0, 0);
      }
    }
  }

  // ---- epilogue: out = O / (l * 0.9) ----
#pragma unroll
  for (int u = 0; u < 2; ++u) {
    float inv[4];
#pragma unroll
    for (int r = 0; r < 4; ++r) inv[r] = 1.0f / (l_r[u][r] * 0.9f);
#pragma unroll
    for (int c = 0; c < 4; ++c)
#pragma unroll
      for (int r = 0; r < 4; ++r)
        out[((size_t)bh * Sn + (size_t)(qbase + u * 64 + w * 16 + quad * 4 + r)) * Dn +
            c * 16 + l16] = o_acc[u][c][r] * inv[r];
  }
}

// ---------------- fallback (R3 kernel, verbatim): used only if ws too small ----------------
constexpr int KST = 72;
__global__ __launch_bounds__(NT) void attn_fallback(
    const float* __restrict__ Q, const float* __restrict__ K,
    const float* __restrict__ V, const int* __restrict__ scale_ptr,
    float* __restrict__ out) {
  __shared__ uint16_t KhS[64 * KST];
  __shared__ uint16_t KlS[64 * KST];
  __shared__ uint16_t VtS[Dn * KST];
  __shared__ uint16_t PSf[4 * 16 * KST];

  const int t = threadIdx.x;
  const int w = t >> 6;
  const int lane = t & 63;
  const int l16 = lane & 15;
  const int quad = lane >> 4;
  const int b = blockIdx.z, h = blockIdx.y;
  const int qbase = blockIdx.x * 64;
  const size_t bh = (size_t)b * Hn + h;
  const float scale = (float)(*scale_ptr);
  const float* Kp = K + bh * Sn * Dn;
  const float* Vp = V + bh * Sn * Dn;

  const int qrow = qbase + w * 16 + l16;
  const float* Qp = Q + (bh * Sn + (size_t)qrow) * Dn;
  s16x8 qh[2], ql[2];
#pragma unroll
  for (int ks = 0; ks < 2; ++ks) {
    const float* src = Qp + ks * 32 + quad * 8;
    float4 x0 = *(const float4*)(src);
    float4 x1 = *(const float4*)(src + 4);
    float xv[8] = {x0.x, x0.y, x0.z, x0.w, x1.x, x1.y, x1.z, x1.w};
#pragma unroll
    for (int j = 0; j < 8; ++j) {
      uint16_t hb = f2bf(xv[j]);
      qh[ks][j] = (short)hb;
      ql[ks][j] = (short)f2bf(xv[j] - bf2f(hb));
    }
  }
  const int kr = t >> 2;
  const int qd = t & 3;
  float m_r[4], l_r[4];
#pragma unroll
  for (int r = 0; r < 4; ++r) { m_r[r] = -INFINITY; l_r[r] = 0.0f; }
  f32x4 o_acc[4];
#pragma unroll
  for (int c = 0; c < 4; ++c) o_acc[c] = (f32x4){0.f, 0.f, 0.f, 0.f};
  const uint32_t rowlin = ((uint32_t)(b * Hn + h)) * (uint32_t)Sn +
                          (uint32_t)(qbase + w * 16 + quad * 4);
  for (int kt = 0; kt < Sn / 64; ++kt) {
    const int kbase = kt * 64;
    __syncthreads();
    {
      const float* ksrc = Kp + (size_t)(kbase + kr) * Dn + qd * 16;
#pragma unroll
      for (int half = 0; half < 2; ++half) {
        float4 a = *(const float4*)(ksrc + half * 8);
        float4 b2 = *(const float4*)(ksrc + half * 8 + 4);
        float xs[8] = {a.x, a.y, a.z, a.w, b2.x, b2.y, b2.z, b2.w};
        s16x8 hv, lv;
#pragma unroll
        for (int j = 0; j < 8; ++j) {
          uint16_t hb = f2bf(xs[j]);
          hv[j] = (short)hb;
          lv[j] = (short)f2bf(xs[j] - bf2f(hb));
        }
        *(s16x8*)&KhS[kr * KST + qd * 16 + half * 8] = hv;
        *(s16x8*)&KlS[kr * KST + qd * 16 + half * 8] = lv;
      }
      const float* vsrc = Vp + (size_t)(kbase + kr) * Dn + qd * 16;
#pragma unroll
      for (int half = 0; half < 2; ++half) {
        float4 a = *(const float4*)(vsrc + half * 8);
        float4 b2 = *(const float4*)(vsrc + half * 8 + 4);
        float xs[8] = {a.x, a.y, a.z, a.w, b2.x, b2.y, b2.z, b2.w};
#pragma unroll
        for (int j = 0; j < 8; ++j)
          VtS[(qd * 16 + half * 8 + j) * KST + kr] = f2bf(xs[j]);
      }
    }
    __syncthreads();
    f32x4 sacc[4];
#pragma unroll
    for (int c = 0; c < 4; ++c) sacc[c] = (f32x4){0.f, 0.f, 0.f, 0.f};
#pragma unroll
    for (int ks = 0; ks < 2; ++ks) {
#pragma unroll
      for (int c = 0; c < 4; ++c) {
        const s16x8 bh_ = *(const s16x8*)&KhS[(c * 16 + l16) * KST + ks * 32 + quad * 8];
        const s16x8 bl_ = *(const s16x8*)&KlS[(c * 16 + l16) * KST + ks * 32 + quad * 8];
        sacc[c] = __builtin_amdgcn_mfma_f32_16x16x32_bf16(qh[ks], bh_, sacc[c], 0, 0, 0);
        sacc[c] = __builtin_amdgcn_mfma_f32_16x16x32_bf16(ql[ks], bh_, sacc[c], 0, 0, 0);
        sacc[c] = __builtin_amdgcn_mfma_f32_16x16x32_bf16(qh[ks], bl_, sacc[c], 0, 0, 0);
      }
    }
    float mx[4];
#pragma unroll
    for (int r = 0; r < 4; ++r) {
      mx[r] = sacc[0][r] * scale;
#pragma unroll
      for (int c = 1; c < 4; ++c) mx[r] = fmaxf(mx[r], sacc[c][r] * scale);
#pragma unroll
      for (int d = 1; d < 16; d <<= 1) mx[r] = fmaxf(mx[r], __shfl_xor(mx[r], d));
    }
    float al[4];
#pragma unroll
    for (int r = 0; r < 4; ++r) {
      const float mn = fmaxf(m_r[r], mx[r]);
      al[r] = __expf(m_r[r] - mn);
      m_r[r] = mn;
    }
#pragma unroll
    for (int c = 0; c < 4; ++c)
#pragma unroll
      for (int r = 0; r < 4; ++r) o_acc[c][r] *= al[r];
    float rs[4] = {0.f, 0.f, 0.f, 0.f};
#pragma unroll
    for (int c = 0; c < 4; ++c) {
#pragma unroll
      for (int r = 0; r < 4; ++r) {
        const float d = sacc[c][r] * scale - m_r[r];
        float pv = __expf(d);
        rs[r] += pv;
        if (d > -25.0f) {
          const uint32_t j = (rowlin + (uint32_t)r) * (uint32_t)Sn +
                             (uint32_t)(kbase + c * 16 + l16);
          if (!keep_bit(j)) pv = 0.0f;
        }
        PSf[(w * 16 + quad * 4 + r) * KST + c * 16 + l16] = f2bf(pv);
      }
    }
#pragma unroll
    for (int r = 0; r < 4; ++r) {
#pragma unroll
      for (int d = 1; d < 16; d <<= 1) rs[r] += __shfl_xor(rs[r], d);
      l_r[r] = l_r[r] * al[r] + rs[r];
    }
#pragma unroll
    for (int ks2 = 0; ks2 < 2; ++ks2) {
      const s16x8 pa = *(const s16x8*)&PSf[(w * 16 + l16) * KST + ks2 * 32 + quad * 8];
#pragma unroll
      for (int c = 0; c < 4; ++c) {
        const s16x8 vb = *(const s16x8*)&VtS[(c * 16 + l16) * KST + ks2 * 32 + quad * 8];
        o_acc[c] = __builtin_amdgcn_mfma_f32_16x16x32_bf16(pa, vb, o_acc[c], 0, 0, 0);
      }
    }
  }
  float inv[4];
#pragma unroll
  for (int r = 0; r < 4; ++r) inv[r] = 1.0f / (l_r[r] * 0.9f);
#pragma unroll
  for (int c = 0; c < 4; ++c)
#pragma unroll
    for (int r = 0; r < 4; ++r)
      out[(bh * Sn + (size_t)(qbase + w * 16 + quad * 4 + r)) * Dn + c * 16 + l16] =
          o_acc[c][r] * inv[r];
}

extern "C" void kernel_launch(void* const* d_in, const int* in_sizes, int n_in,
                              void* d_out, int out_size, void* d_ws, size_t ws_size,
                              hipStream_t stream) {
  const float* Q = (const float*)d_in[0];
  const float* K = (const float*)d_in[1];
  const float* V = (const float*)d_in[2];
  const int* sf = (const int*)d_in[3];
  float* out = (float*)d_out;

  constexpr size_t ARR = (size_t)Bn * Hn * Sn * Dn;  // 4,194,304 elems (8 MB bf16)
  const size_t need = 3 * ARR * sizeof(uint16_t);    // 24 MB

  if (ws_size >= need) {
    uint16_t* Khg = (uint16_t*)d_ws;
    uint16_t* Klg = Khg + ARR;
    uint16_t* Vtg = Klg + ARR;
    prep_kv<<<dim3(16, 64), NT, 0, stream>>>(K, V, Khg, Klg, Vtg);
    attn_mfma2<<<dim3(Sn / TQ, Hn, Bn), NT, 0, stream>>>(Q, Khg, Klg, Vtg, sf, out);
  } else {
    attn_fallback<<<dim3(Sn / 64, Hn, Bn), NT, 0, stream>>>(Q, K, V, sf, out);
  }
}

// Round 5
// 196.870 us; speedup vs baseline: 2.3204x; 1.0545x over previous
//
#include <hip/hip_runtime.h>
#include <stdint.h>
#include <math.h>

// Attention: out = dropout(softmax(8 * Q K^T)) V, B=4 H=16 S=1024 D=64 fp32.
// R5 structure:
//  - prep_kv: K -> (Kh,Kl) bf16 split, V -> V^T, swizzled bf16 tiles in d_ws
//    (chunk c of row r stored at c^(r&7)) -> attn kernel DMAs via
//    global_load_lds (lane-contiguous) and reads B-frags conflict-free.
//  - attn_mfma3: TQ=128 flash sweep with UNMASKED PV. Dropout handled by
//    deferred correction: near-max entries (dv > -11 vs running max, a
//    superset of final) pushed to a per-wave LDS list via ballot+popc
//    (no per-tile threefry!). After the sweep: dense keep_bit batch over the
//    list, then wave-serial subtraction of dropped p*V from o_acc.
//    Threefry: counter-mode, bits = y0^y1 (VERIFIED R2). Skipped entries
//    (p < ~1.7e-5) contribute <= ~1e-4 masked or not.

constexpr int Bn = 4, Hn = 16, Sn = 1024, Dn = 64;
constexpr int NT = 256;
constexpr int TQ = 128, TK = 64;
constexpr int PST = 72;   // PS row stride in bf16
constexpr int CAP = 512;  // per-wave candidate list capacity

typedef short s16x8 __attribute__((ext_vector_type(8)));
typedef float f32x4 __attribute__((ext_vector_type(4)));

__device__ __forceinline__ uint16_t f2bf(float x) {  // RNE float->bf16
  uint32_t u = __float_as_uint(x);
  return (uint16_t)((u + 0x7fffu + ((u >> 16) & 1u)) >> 16);
}
__device__ __forceinline__ float bf2f(uint16_t h) {
  return __uint_as_float(((uint32_t)h) << 16);
}

__device__ __forceinline__ void tf_round(uint32_t& x0, uint32_t& x1, const int r) {
  x0 += x1;
  x1 = (x1 << r) | (x1 >> (32 - r));
  x1 ^= x0;
}

// threefry2x32, key(42)=(0,42), counter (0, j), bits = y0^y1  [VERIFIED R2]
__device__ __noinline__ int keep_bit(uint32_t j) {
  uint32_t x0 = 0u, x1 = j;
  const uint32_t k0 = 0u, k1v = 42u;
  const uint32_t k2v = k0 ^ k1v ^ 0x1BD11BDAu;
  x0 += k0; x1 += k1v;
  tf_round(x0, x1, 13); tf_round(x0, x1, 15); tf_round(x0, x1, 26); tf_round(x0, x1, 6);
  x0 += k1v; x1 += k2v + 1u;
  tf_round(x0, x1, 17); tf_round(x0, x1, 29); tf_round(x0, x1, 16); tf_round(x0, x1, 24);
  x0 += k2v; x1 += k0 + 2u;
  tf_round(x0, x1, 13); tf_round(x0, x1, 15); tf_round(x0, x1, 26); tf_round(x0, x1, 6);
  x0 += k0; x1 += k1v + 3u;
  tf_round(x0, x1, 17); tf_round(x0, x1, 29); tf_round(x0, x1, 16); tf_round(x0, x1, 24);
  x0 += k1v; x1 += k2v + 4u;
  tf_round(x0, x1, 13); tf_round(x0, x1, 15); tf_round(x0, x1, 26); tf_round(x0, x1, 6);
  x0 += k2v; x1 += k0 + 5u;
  uint32_t bits = x0 ^ x1;
  float u = __uint_as_float((bits >> 9) | 0x3f800000u) - 1.0f;
  return u < 0.9f;
}

// ---------------- pre-pass: K split + V transpose, swizzled bf16 tiles ----------------
__global__ __launch_bounds__(NT) void prep_kv(const float* __restrict__ K,
                                              const float* __restrict__ V,
                                              uint16_t* __restrict__ Khg,
                                              uint16_t* __restrict__ Klg,
                                              uint16_t* __restrict__ Vtg) {
  __shared__ float Vl[TK][Dn + 1];
  const int t = threadIdx.x;
  const int kt = blockIdx.x;   // 0..15
  const int bh = blockIdx.y;   // 0..63
  const int r = t >> 2, qd = t & 3;
  const size_t tile = ((size_t)bh * 16 + kt) * 4096;
  const float* ksrc = K + ((size_t)bh * Sn + (size_t)(kt * TK + r)) * Dn + qd * 16;
  const float* vsrc = V + ((size_t)bh * Sn + (size_t)(kt * TK + r)) * Dn + qd * 16;

#pragma unroll
  for (int half = 0; half < 2; ++half) {
    float4 a = *(const float4*)(ksrc + half * 8);
    float4 b = *(const float4*)(ksrc + half * 8 + 4);
    float xs[8] = {a.x, a.y, a.z, a.w, b.x, b.y, b.z, b.w};
    s16x8 hv, lv;
#pragma unroll
    for (int j = 0; j < 8; ++j) {
      uint16_t hb = f2bf(xs[j]);
      hv[j] = (short)hb;
      lv[j] = (short)f2bf(xs[j] - bf2f(hb));
    }
    const int sc = (qd * 2 + half) ^ (r & 7);
    *(s16x8*)&Khg[tile + (size_t)r * 64 + sc * 8] = hv;
    *(s16x8*)&Klg[tile + (size_t)r * 64 + sc * 8] = lv;
    float4 va = *(const float4*)(vsrc + half * 8);
    float4 vb = *(const float4*)(vsrc + half * 8 + 4);
    *(float4*)&Vl[r][qd * 16 + half * 8] = va;
    *(float4*)&Vl[r][qd * 16 + half * 8 + 4] = vb;
  }
  __syncthreads();
#pragma unroll
  for (int half = 0; half < 2; ++half) {
    s16x8 ov;
#pragma unroll
    for (int j = 0; j < 8; ++j) ov[j] = (short)f2bf(Vl[qd * 16 + half * 8 + j][r]);
    const int sc = (qd * 2 + half) ^ (r & 7);
    *(s16x8*)&Vtg[tile + (size_t)r * 64 + sc * 8] = ov;
  }
}

// ---------------- main flash kernel, TQ=128, deferred dropout ----------------
__global__ __launch_bounds__(NT) void attn_mfma3(
    const float* __restrict__ Q, const uint16_t* __restrict__ Khg,
    const uint16_t* __restrict__ Klg, const uint16_t* __restrict__ Vtg,
    const float* __restrict__ V, const int* __restrict__ scale_ptr,
    float* __restrict__ out) {
  __shared__ uint16_t KhS[TK * Dn];      // 8 KB, unpadded (DMA dest), swizzled rows
  __shared__ uint16_t KlS[TK * Dn];
  __shared__ uint16_t VtS[Dn * TK];
  __shared__ uint16_t PS[4 * 32 * PST];  // per-wave P, padded stride
  __shared__ uint32_t Lm[4][CAP];        // per-wave candidate list: (rw<<10)|col
  __shared__ float Lsv[4][CAP];          // candidate logit s
  __shared__ float mfin[4][32];          // per-wave final row max

  const int t = threadIdx.x;
  const int w = t >> 6;
  const int lane = t & 63;
  const int l16 = lane & 15;
  const int quad = lane >> 4;

  const int b = blockIdx.z, h = blockIdx.y;
  const int qbase = blockIdx.x * TQ;
  const int bh = b * Hn + h;
  const float qscale = (float)(*scale_ptr);

  // ---- Q A-frags (pre-scaled), 2 row-sets of 16 per wave ----
  s16x8 qh[2][2], ql[2][2];
#pragma unroll
  for (int u = 0; u < 2; ++u) {
    const int qrow = qbase + u * 64 + w * 16 + l16;
    const float* src = Q + ((size_t)bh * Sn + (size_t)qrow) * Dn;
#pragma unroll
    for (int ks = 0; ks < 2; ++ks) {
      float4 x0 = *(const float4*)(src + ks * 32 + quad * 8);
      float4 x1 = *(const float4*)(src + ks * 32 + quad * 8 + 4);
      float xv[8] = {x0.x, x0.y, x0.z, x0.w, x1.x, x1.y, x1.z, x1.w};
#pragma unroll
      for (int j = 0; j < 8; ++j) {
        const float xs = xv[j] * qscale;
        uint16_t hb = f2bf(xs);
        qh[u][ks][j] = (short)hb;
        ql[u][ks][j] = (short)f2bf(xs - bf2f(hb));
      }
    }
  }

  float m_r[2][4], l_r[2][4];
#pragma unroll
  for (int u = 0; u < 2; ++u)
#pragma unroll
    for (int r = 0; r < 4; ++r) { m_r[u][r] = -INFINITY; l_r[u][r] = 0.0f; }
  f32x4 o_acc[2][4];
#pragma unroll
  for (int u = 0; u < 2; ++u)
#pragma unroll
    for (int c = 0; c < 4; ++c) o_acc[u][c] = (f32x4){0.f, 0.f, 0.f, 0.f};

  const uint32_t hbase = (uint32_t)bh * (uint32_t)Sn;
  int lbase = 0;  // per-wave list fill (wave-uniform)

  for (int kt = 0; kt < Sn / TK; ++kt) {
    const int kbase = kt * TK;
    __syncthreads();

    // ---- DMA staging ----
    {
      const size_t tile = ((size_t)bh * 16 + kt) * 4096;
#pragma unroll
      for (int s = 0; s < 2; ++s) {
        const int eoff = (w * 2 + s) * 512 + lane * 8;
        __builtin_amdgcn_global_load_lds(
            (const __attribute__((address_space(1))) uint32_t*)(Khg + tile + eoff),
            (__attribute__((address_space(3))) uint32_t*)(KhS + eoff), 16, 0, 0);
        __builtin_amdgcn_global_load_lds(
            (const __attribute__((address_space(1))) uint32_t*)(Klg + tile + eoff),
            (__attribute__((address_space(3))) uint32_t*)(KlS + eoff), 16, 0, 0);
        __builtin_amdgcn_global_load_lds(
            (const __attribute__((address_space(1))) uint32_t*)(Vtg + tile + eoff),
            (__attribute__((address_space(3))) uint32_t*)(VtS + eoff), 16, 0, 0);
      }
    }
    __syncthreads();

    // ---- QK^T: split-bf16 3-MFMA ----
    f32x4 sacc[2][4];
#pragma unroll
    for (int u = 0; u < 2; ++u)
#pragma unroll
      for (int c = 0; c < 4; ++c) sacc[u][c] = (f32x4){0.f, 0.f, 0.f, 0.f};
#pragma unroll
    for (int ks = 0; ks < 2; ++ks) {
#pragma unroll
      for (int c = 0; c < 4; ++c) {
        const int boff = (c * 16 + l16) * 64 + (((ks * 4 + quad) ^ (l16 & 7)) * 8);
        const s16x8 bhv = *(const s16x8*)&KhS[boff];
        const s16x8 blv = *(const s16x8*)&KlS[boff];
#pragma unroll
        for (int u = 0; u < 2; ++u) {
          sacc[u][c] = __builtin_amdgcn_mfma_f32_16x16x32_bf16(qh[u][ks], bhv, sacc[u][c], 0, 0, 0);
          sacc[u][c] = __builtin_amdgcn_mfma_f32_16x16x32_bf16(ql[u][ks], bhv, sacc[u][c], 0, 0, 0);
          sacc[u][c] = __builtin_amdgcn_mfma_f32_16x16x32_bf16(qh[u][ks], blv, sacc[u][c], 0, 0, 0);
        }
      }
    }

    // ---- online softmax + candidate push (NO threefry here) ----
#pragma unroll
    for (int u = 0; u < 2; ++u) {
      float mx[4], al[4];
#pragma unroll
      for (int r = 0; r < 4; ++r) {
        mx[r] = fmaxf(fmaxf(sacc[u][0][r], sacc[u][1][r]),
                      fmaxf(sacc[u][2][r], sacc[u][3][r]));
#pragma unroll
        for (int d = 1; d < 16; d <<= 1) mx[r] = fmaxf(mx[r], __shfl_xor(mx[r], d));
        const float mn = fmaxf(m_r[u][r], mx[r]);
        al[r] = __expf(m_r[u][r] - mn);
        m_r[u][r] = mn;
      }
#pragma unroll
      for (int c = 0; c < 4; ++c)
#pragma unroll
        for (int r = 0; r < 4; ++r) o_acc[u][c][r] *= al[r];

      float rs[4] = {0.f, 0.f, 0.f, 0.f};
#pragma unroll
      for (int r = 0; r < 4; ++r) {
        float dv[4], pv[4];
#pragma unroll
        for (int c = 0; c < 4; ++c) {
          dv[c] = sacc[u][c][r] - m_r[u][r];
          pv[c] = __expf(dv[c]);
          rs[r] += pv[c];  // UNMASKED row sum
        }
        const float dmx = fmaxf(fmaxf(dv[0], dv[1]), fmaxf(dv[2], dv[3]));
        if (__ballot(dmx > -11.0f) != 0ull) {
#pragma unroll
          for (int c = 0; c < 4; ++c) {
            const uint64_t mc = __ballot(dv[c] > -11.0f);
            if (mc != 0ull) {
              if (lbase + 64 <= CAP) {
                const int slot = lbase + (int)__popcll(mc & ((1ull << lane) - 1ull));
                if (dv[c] > -11.0f) {
                  const uint32_t rw = (uint32_t)(u * 16 + quad * 4 + r);
                  Lm[w][slot] = (rw << 10) | (uint32_t)(kbase + c * 16 + l16);
                  Lsv[w][slot] = dv[c] + m_r[u][r];
                }
                lbase += (int)__popcll(mc);
              } else if (dv[c] > -11.0f) {  // overflow fallback: inline dropout
                const uint32_t j =
                    (hbase + (uint32_t)(qbase + u * 64 + w * 16 + quad * 4 + r)) *
                        (uint32_t)Sn +
                    (uint32_t)(kbase + c * 16 + l16);
                if (!keep_bit(j)) pv[c] = 0.0f;
              }
            }
          }
        }
        const int prow = (w * 32 + u * 16 + quad * 4 + r) * PST;
#pragma unroll
        for (int c = 0; c < 4; ++c) PS[prow + c * 16 + l16] = f2bf(pv[c]);
      }
#pragma unroll
      for (int r = 0; r < 4; ++r) {
#pragma unroll
        for (int d = 1; d < 16; d <<= 1) rs[r] += __shfl_xor(rs[r], d);
        l_r[u][r] = l_r[u][r] * al[r] + rs[r];
      }
    }

    // ---- PV: O += P V (unmasked) ----
#pragma unroll
    for (int ks2 = 0; ks2 < 2; ++ks2) {
      s16x8 pa[2];
#pragma unroll
      for (int u = 0; u < 2; ++u)
        pa[u] = *(const s16x8*)&PS[(w * 32 + u * 16 + l16) * PST + ks2 * 32 + quad * 8];
#pragma unroll
      for (int c = 0; c < 4; ++c) {
        const int voff = (c * 16 + l16) * 64 + (((ks2 * 4 + quad) ^ (l16 & 7)) * 8);
        const s16x8 vb = *(const s16x8*)&VtS[voff];
#pragma unroll
        for (int u = 0; u < 2; ++u)
          o_acc[u][c] = __builtin_amdgcn_mfma_f32_16x16x32_bf16(pa[u], vb, o_acc[u][c], 0, 0, 0);
      }
    }
  }

  // ---- drain: dense threefry over the candidate list, subtract dropped ----
  if (l16 == 0) {
#pragma unroll
    for (int u = 0; u < 2; ++u)
#pragma unroll
      for (int r = 0; r < 4; ++r) mfin[w][u * 16 + quad * 4 + r] = m_r[u][r];
  }
  for (int e0 = 0; e0 < lbase; e0 += 64) {
    const int e = e0 + lane;
    const bool valid = e < lbase;
    const uint32_t meta = valid ? Lm[w][e] : 0u;
    const float sv = valid ? Lsv[w][e] : 0.0f;
    const uint32_t rwv = meta >> 10, keyv = meta & 1023u;
    const uint32_t grow = (uint32_t)qbase + (rwv >> 4) * 64u + (uint32_t)(w * 16) + (rwv & 15u);
    const uint32_t j = (hbase + grow) * (uint32_t)Sn + keyv;
    const int kb = keep_bit(j);  // dense: all 64 lanes productive
    uint64_t dm = __ballot(valid && !kb);
    while (dm != 0ull) {
      const int src = (int)__builtin_ctzll(dm);
      dm &= dm - 1ull;
      const uint32_t meta_s = (uint32_t)__builtin_amdgcn_readlane((int)meta, src);
      const float sv_s =
          __uint_as_float((uint32_t)__builtin_amdgcn_readlane((int)__float_as_uint(sv), src));
      const int rw = (int)(meta_s >> 10);
      const int key = (int)(meta_s & 1023u);
      const int urw = rw >> 4, rr = rw & 3, qo = (rw >> 2) & 3;
      const float p = __expf(sv_s - mfin[w][rw]);
      const float pb = bf2f(f2bf(p));
      const float* vp = V + ((size_t)bh * Sn + (size_t)key) * Dn;
#pragma unroll
      for (int u = 0; u < 2; ++u)
        if (u == urw) {
#pragma unroll
          for (int r = 0; r < 4; ++r)
            if (r == rr) {
              if (quad == qo) {
#pragma unroll
                for (int c = 0; c < 4; ++c) {
                  const float vv = bf2f(f2bf(vp[c * 16 + l16]));
                  o_acc[u][c][r] = fmaf(-pb, vv, o_acc[u][c][r]);
                }
              }
            }
        }
    }
  }

  // ---- epilogue: out = O / (l * 0.9) ----
#pragma unroll
  for (int u = 0; u < 2; ++u) {
    float inv[4];
#pragma unroll
    for (int r = 0; r < 4; ++r) inv[r] = 1.0f / (l_r[u][r] * 0.9f);
#pragma unroll
    for (int c = 0; c < 4; ++c)
#pragma unroll
      for (int r = 0; r < 4; ++r)
        out[((size_t)bh * Sn + (size_t)(qbase + u * 64 + w * 16 + quad * 4 + r)) * Dn +
            c * 16 + l16] = o_acc[u][c][r] * inv[r];
  }
}

// ---------------- fallback (R3 kernel, verbatim): used only if ws too small ----------------
constexpr int KST = 72;
__global__ __launch_bounds__(NT) void attn_fallback(
    const float* __restrict__ Q, const float* __restrict__ K,
    const float* __restrict__ V, const int* __restrict__ scale_ptr,
    float* __restrict__ out) {
  __shared__ uint16_t KhS[64 * KST];
  __shared__ uint16_t KlS[64 * KST];
  __shared__ uint16_t VtS[Dn * KST];
  __shared__ uint16_t PSf[4 * 16 * KST];

  const int t = threadIdx.x;
  const int w = t >> 6;
  const int lane = t & 63;
  const int l16 = lane & 15;
  const int quad = lane >> 4;
  const int b = blockIdx.z, h = blockIdx.y;
  const int qbase = blockIdx.x * 64;
  const size_t bh = (size_t)b * Hn + h;
  const float scale = (float)(*scale_ptr);
  const float* Kp = K + bh * Sn * Dn;
  const float* Vp = V + bh * Sn * Dn;

  const int qrow = qbase + w * 16 + l16;
  const float* Qp = Q + (bh * Sn + (size_t)qrow) * Dn;
  s16x8 qh[2], ql[2];
#pragma unroll
  for (int ks = 0; ks < 2; ++ks) {
    const float* src = Qp + ks * 32 + quad * 8;
    float4 x0 = *(const float4*)(src);
    float4 x1 = *(const float4*)(src + 4);
    float xv[8] = {x0.x, x0.y, x0.z, x0.w, x1.x, x1.y, x1.z, x1.w};
#pragma unroll
    for (int j = 0; j < 8; ++j) {
      uint16_t hb = f2bf(xv[j]);
      qh[ks][j] = (short)hb;
      ql[ks][j] = (short)f2bf(xv[j] - bf2f(hb));
    }
  }
  const int kr = t >> 2;
  const int qd = t & 3;
  float m_r[4], l_r[4];
#pragma unroll
  for (int r = 0; r < 4; ++r) { m_r[r] = -INFINITY; l_r[r] = 0.0f; }
  f32x4 o_acc[4];
#pragma unroll
  for (int c = 0; c < 4; ++c) o_acc[c] = (f32x4){0.f, 0.f, 0.f, 0.f};
  const uint32_t rowlin = ((uint32_t)(b * Hn + h)) * (uint32_t)Sn +
                          (uint32_t)(qbase + w * 16 + quad * 4);
  for (int kt = 0; kt < Sn / 64; ++kt) {
    const int kbase = kt * 64;
    __syncthreads();
    {
      const float* ksrc = Kp + (size_t)(kbase + kr) * Dn + qd * 16;
#pragma unroll
      for (int half = 0; half < 2; ++half) {
        float4 a = *(const float4*)(ksrc + half * 8);
        float4 b2 = *(const float4*)(ksrc + half * 8 + 4);
        float xs[8] = {a.x, a.y, a.z, a.w, b2.x, b2.y, b2.z, b2.w};
        s16x8 hv, lv;
#pragma unroll
        for (int j = 0; j < 8; ++j) {
          uint16_t hb = f2bf(xs[j]);
          hv[j] = (short)hb;
          lv[j] = (short)f2bf(xs[j] - bf2f(hb));
        }
        *(s16x8*)&KhS[kr * KST + qd * 16 + half * 8] = hv;
        *(s16x8*)&KlS[kr * KST + qd * 16 + half * 8] = lv;
      }
      const float* vsrc = Vp + (size_t)(kbase + kr) * Dn + qd * 16;
#pragma unroll
      for (int half = 0; half < 2; ++half) {
        float4 a = *(const float4*)(vsrc + half * 8);
        float4 b2 = *(const float4*)(vsrc + half * 8 + 4);
        float xs[8] = {a.x, a.y, a.z, a.w, b2.x, b2.y, b2.z, b2.w};
#pragma unroll
        for (int j = 0; j < 8; ++j)
          VtS[(qd * 16 + half * 8 + j) * KST + kr] = f2bf(xs[j]);
      }
    }
    __syncthreads();
    f32x4 sacc[4];
#pragma unroll
    for (int c = 0; c < 4; ++c) sacc[c] = (f32x4){0.f, 0.f, 0.f, 0.f};
#pragma unroll
    for (int ks = 0; ks < 2; ++ks) {
#pragma unroll
      for (int c = 0; c < 4; ++c) {
        const s16x8 bh_ = *(const s16x8*)&KhS[(c * 16 + l16) * KST + ks * 32 + quad * 8];
        const s16x8 bl_ = *(const s16x8*)&KlS[(c * 16 + l16) * KST + ks * 32 + quad * 8];
        sacc[c] = __builtin_amdgcn_mfma_f32_16x16x32_bf16(qh[ks], bh_, sacc[c], 0, 0, 0);
        sacc[c] = __builtin_amdgcn_mfma_f32_16x16x32_bf16(ql[ks], bh_, sacc[c], 0, 0, 0);
        sacc[c] = __builtin_amdgcn_mfma_f32_16x16x32_bf16(qh[ks], bl_, sacc[c], 0, 0, 0);
      }
    }
    float mx[4];
#pragma unroll
    for (int r = 0; r < 4; ++r) {
      mx[r] = sacc[0][r] * scale;
#pragma unroll
      for (int c = 1; c < 4; ++c) mx[r] = fmaxf(mx[r], sacc[c][r] * scale);
#pragma unroll
      for (int d = 1; d < 16; d <<= 1) mx[r] = fmaxf(mx[r], __shfl_xor(mx[r], d));
    }
    float al[4];
#pragma unroll
    for (int r = 0; r < 4; ++r) {
      const float mn = fmaxf(m_r[r], mx[r]);
      al[r] = __expf(m_r[r] - mn);
      m_r[r] = mn;
    }
#pragma unroll
    for (int c = 0; c < 4; ++c)
#pragma unroll
      for (int r = 0; r < 4; ++r) o_acc[c][r] *= al[r];
    float rs[4] = {0.f, 0.f, 0.f, 0.f};
#pragma unroll
    for (int c = 0; c < 4; ++c) {
#pragma unroll
      for (int r = 0; r < 4; ++r) {
        const float d = sacc[c][r] * scale - m_r[r];
        float pv = __expf(d);
        rs[r] += pv;
        if (d > -25.0f) {
          const uint32_t j = (rowlin + (uint32_t)r) * (uint32_t)Sn +
                             (uint32_t)(kbase + c * 16 + l16);
          if (!keep_bit(j)) pv = 0.0f;
        }
        PSf[(w * 16 + quad * 4 + r) * KST + c * 16 + l16] = f2bf(pv);
      }
    }
#pragma unroll
    for (int r = 0; r < 4; ++r) {
#pragma unroll
      for (int d = 1; d < 16; d <<= 1) rs[r] += __shfl_xor(rs[r], d);
      l_r[r] = l_r[r] * al[r] + rs[r];
    }
#pragma unroll
    for (int ks2 = 0; ks2 < 2; ++ks2) {
      const s16x8 pa = *(const s16x8*)&PSf[(w * 16 + l16) * KST + ks2 * 32 + quad * 8];
#pragma unroll
      for (int c = 0; c < 4; ++c) {
        const s16x8 vb = *(const s16x8*)&VtS[(c * 16 + l16) * KST + ks2 * 32 + quad * 8];
        o_acc[c] = __builtin_amdgcn_mfma_f32_16x16x32_bf16(pa, vb, o_acc[c], 0, 0, 0);
      }
    }
  }
  float inv[4];
#pragma unroll
  for (int r = 0; r < 4; ++r) inv[r] = 1.0f / (l_r[r] * 0.9f);
#pragma unroll
  for (int c = 0; c < 4; ++c)
#pragma unroll
    for (int r = 0; r < 4; ++r)
      out[(bh * Sn + (size_t)(qbase + w * 16 + quad * 4 + r)) * Dn + c * 16 + l16] =
          o_acc[c][r] * inv[r];
}

extern "C" void kernel_launch(void* const* d_in, const int* in_sizes, int n_in,
                              void* d_out, int out_size, void* d_ws, size_t ws_size,
                              hipStream_t stream) {
  const float* Q = (const float*)d_in[0];
  const float* K = (const float*)d_in[1];
  const float* V = (const float*)d_in[2];
  const int* sf = (const int*)d_in[3];
  float* out = (float*)d_out;

  constexpr size_t ARR = (size_t)Bn * Hn * Sn * Dn;  // 4,194,304 elems (8 MB bf16)
  const size_t need = 3 * ARR * sizeof(uint16_t);    // 24 MB

  if (ws_size >= need) {
    uint16_t* Khg = (uint16_t*)d_ws;
    uint16_t* Klg = Khg + ARR;
    uint16_t* Vtg = Klg + ARR;
    prep_kv<<<dim3(16, 64), NT, 0, stream>>>(K, V, Khg, Klg, Vtg);
    attn_mfma3<<<dim3(Sn / TQ, Hn, Bn), NT, 0, stream>>>(Q, Khg, Klg, Vtg, V, sf, out);
  } else {
    attn_fallback<<<dim3(Sn / 64, Hn, Bn), NT, 0, stream>>>(Q, K, V, sf, out);
  }
}